// Round 4
// baseline (302.179 us; speedup 1.0000x reference)
//
#include <hip/hip_runtime.h>
#include <math.h>

// Gaussian blur 21x21, sigma=5, depthwise [B=32,C=3,H=512,W=512] fp32, reflect pad.
//
// R4: occupancy attack. rocprof R3: Occupancy 30%, VALUBusy 32%, HBM 20%,
// LDS+VALU+HBM budgets all << duration => latency-bound at 3 blocks/CU.
//   - drop s_in (29.6 KB): horizontal pass reads aligned float4 directly from
//     global; the 6x overlap between neighboring threads is served by L1/L2.
//   - LDS = s_h only (22.8 KB) -> 6 blocks/CU (__launch_bounds__(256,6)),
//     one barrier instead of two.
//   - vertical pass unchanged from R3: scalar column sliding window,
//     conflict-free ds_read_b32, coalesced 256B/wave stores.

#define KS    21
#define PAD   10
#define TILE  64
#define LW    (TILE + 2 * PAD)   // 84 rows of s_h (with y-halo)
#define SKEW  2                  // xbase = x0-12 -> float4-aligned
#define SH    68                 // s_h padded row stride
#define IMG_H 512
#define IMG_W 512
#define NT    256

__global__ __launch_bounds__(NT, 6) void gauss_blur_kernel(
    const float* __restrict__ in, float* __restrict__ out)
{
    __shared__ __align__(16) float s_h[LW * SH];   // 84*68*4 = 22848 B

    // Normalized 1-D Gaussian (outer-product normalization == 1-D norm squared)
    float w[KS];
    {
        float s = 0.f;
#pragma unroll
        for (int k = 0; k < KS; ++k) {
            float d = (float)(k - PAD);
            w[k] = expf(-d * d * (1.0f / 50.0f));  // 2*sigma^2 = 50
            s += w[k];
        }
        float inv = 1.0f / s;
#pragma unroll
        for (int k = 0; k < KS; ++k) w[k] *= inv;
    }

    const int tid   = threadIdx.x;
    const int plane = blockIdx.z;                 // b*C + c, 0..95
    const int x0    = blockIdx.x * TILE;
    const int y0    = blockIdx.y * TILE;
    const int xbase = x0 - PAD - SKEW;            // -12..436, == 0 mod 4

    const float* __restrict__ pin = in + (size_t)plane * (IMG_H * IMG_W);

    // block-uniform: do all 28 halo cols fit in-bounds for vector loads?
    const bool xint = (xbase >= 0) && (xbase + 88 <= IMG_W);   // bx = 1..6

    // ---- phase 1: horizontal 21-tap, global -> s_h, 4 outputs/thread ----
    // 84 rows x 16 col-groups = 1344 items, 5.25 iters/thread
    for (int idx = tid; idx < LW * (TILE / 4); idx += NT) {
        int ly = idx >> 4;            // s_h row 0..83
        int lx = (idx & 15) << 2;     // out col 0,4,...,60
        int gy = y0 + ly - PAD;
        gy = (gy < 0) ? -gy : ((gy >= IMG_H) ? (2 * IMG_H - 2 - gy) : gy);
        const float* __restrict__ rowp = pin + (size_t)gy * IMG_W;

        float v[28];
        if (xint) {
            const float4* rp = (const float4*)(rowp + xbase + lx);  // aligned
#pragma unroll
            for (int t = 0; t < 7; ++t) {
                float4 f = rp[t];
                v[4 * t + 0] = f.x; v[4 * t + 1] = f.y;
                v[4 * t + 2] = f.z; v[4 * t + 3] = f.w;
            }
        } else {
            // x-edge blocks (bx 0 or 7): scalar loads with x-reflect.
            // Only v[2..25] are consumed below.
#pragma unroll
            for (int d = 0; d < 24; ++d) {
                int gx = xbase + lx + 2 + d;
                gx = (gx < 0) ? -gx : ((gx >= IMG_W) ? (2 * IMG_W - 2 - gx) : gx);
                v[d + 2] = rowp[gx];
            }
            v[0] = v[1] = v[26] = v[27] = 0.f;
        }

        float a0 = 0.f, a1 = 0.f, a2 = 0.f, a3 = 0.f;
#pragma unroll
        for (int k = 0; k < KS; ++k) {
            float wk = w[k];
            a0 += wk * v[k + 2];
            a1 += wk * v[k + 3];
            a2 += wk * v[k + 4];
            a3 += wk * v[k + 5];
        }
        *(float4*)&s_h[ly * SH + lx] = make_float4(a0, a1, a2, a3);
    }
    __syncthreads();

    // ---- phase 2: vertical 21-tap, 1 col x 16 rows per thread ----
    // Wave lanes cover 64 consecutive columns -> 2-way bank aliasing (free).
    {
        const int c  = tid & 63;              // column 0..63
        const int rb = (tid >> 6) << 4;       // row base 0,16,32,48

        float acc[16];
#pragma unroll
        for (int r = 0; r < 16; ++r) acc[r] = 0.f;

#pragma unroll
        for (int t = 0; t < KS + 15; ++t) {   // 36 s_h rows
            float v = s_h[(rb + t) * SH + c];
#pragma unroll
            for (int r = 0; r < 16; ++r) {
                int k = t - r;
                if (k >= 0 && k < KS) acc[r] += w[k] * v;
            }
        }

        float* __restrict__ pout = out + (size_t)plane * (IMG_H * IMG_W)
                                       + (size_t)(y0 + rb) * IMG_W + (x0 + c);
#pragma unroll
        for (int r = 0; r < 16; ++r) pout[r * IMG_W] = acc[r];  // 256B/wave
    }
}

extern "C" void kernel_launch(void* const* d_in, const int* in_sizes, int n_in,
                              void* d_out, int out_size, void* d_ws, size_t ws_size,
                              hipStream_t stream)
{
    const float* x = (const float*)d_in[0];
    float* out = (float*)d_out;

    dim3 grid(IMG_W / TILE, IMG_H / TILE, 96);   // 8 x 8 x (32*3) planes
    dim3 block(NT);
    gauss_blur_kernel<<<grid, block, 0, stream>>>(x, out);
}

// Round 5
// 228.715 us; speedup vs baseline: 1.3212x; 1.3212x over previous
//
#include <hip/hip_runtime.h>
#include <math.h>

// Gaussian blur 21x21, sigma=5, depthwise [B=32,C=3,H=512,W=512] fp32, reflect pad.
//
// R5: bank-conflict stride-class fix, isolated A/B vs R3.
// Evidence: R3 (s_in stride 88 w ≡ 24 mod 32) -> 1.9e7 conflict cycles, all
// attributable to stage2 ds_read_b128 (4 rows x 16 chunks per wave). R4 showed
// the same wave pattern at row stride ≡ +4 mod 32 (s_h, 68 w) has ZERO
// conflicts. So: s_in stride 88 -> 92 (≡ -4 mod 32, keeps 16B alignment),
// s_h stride 68 -> 64 (stage3 reads are lane-consecutive b32, stride-agnostic;
// LDS writes empirically conflict-free). Total LDS unchanged: 52416 B ->
// 3 blocks/CU, same occupancy as R3. Everything else identical to R3.

#define KS    21
#define PAD   10
#define TILE  64
#define LW    (TILE + 2 * PAD)   // 84 tile rows (with halo)
#define SKEW  2                  // xbase = x0-12 -> float4-aligned
#define LWX   92                 // s_in row stride: 92 ≡ -4 mod 32 (conflict-free class)
#define SH    64                 // s_h row stride
#define IMG_H 512
#define IMG_W 512
#define NT    256

__global__ __launch_bounds__(NT) void gauss_blur_kernel(
    const float* __restrict__ in, float* __restrict__ out)
{
    __shared__ __align__(16) float s_in[LW * LWX];  // 84*92*4 = 30912 B
    __shared__ __align__(16) float s_h [LW * SH];   // 84*64*4 = 21504 B
    // total 52416 B -> 3 blocks/CU (same as R3)

    // Normalized 1-D Gaussian (outer-product normalization == 1-D norm squared)
    float w[KS];
    {
        float s = 0.f;
#pragma unroll
        for (int k = 0; k < KS; ++k) {
            float d = (float)(k - PAD);
            w[k] = expf(-d * d * (1.0f / 50.0f));  // 2*sigma^2 = 50
            s += w[k];
        }
        float inv = 1.0f / s;
#pragma unroll
        for (int k = 0; k < KS; ++k) w[k] *= inv;
    }

    const int tid   = threadIdx.x;
    const int plane = blockIdx.z;                 // b*C + c, 0..95
    const int x0    = blockIdx.x * TILE;
    const int y0    = blockIdx.y * TILE;
    const int xbase = x0 - PAD - SKEW;            // -12..436, == 0 mod 4

    const float* __restrict__ pin = in + (size_t)plane * (IMG_H * IMG_W);

    // ---- stage 1: global -> LDS ----
    if (xbase >= 0 && xbase + LWX <= IMG_W) {
        // interior in x (bx=1..6): aligned float4 loads, y reflect per row
        for (int idx = tid; idx < LW * (LWX / 4); idx += NT) {
            int ly = idx / (LWX / 4);
            int q  = idx - ly * (LWX / 4);
            int gy = y0 + ly - PAD;
            gy = (gy < 0) ? -gy : ((gy >= IMG_H) ? (2 * IMG_H - 2 - gy) : gy);
            float4 v = *(const float4*)&pin[gy * IMG_W + xbase + 4 * q];
            *(float4*)&s_in[ly * LWX + 4 * q] = v;
        }
    } else {
        // x-edge blocks (bx==0 or 7): scalar reflect path
        for (int idx = tid; idx < LW * LWX; idx += NT) {
            int ly = idx / LWX;
            int j  = idx - ly * LWX;
            int gy = y0 + ly - PAD;
            int gx = xbase + j;
            gy = (gy < 0) ? -gy : ((gy >= IMG_H) ? (2 * IMG_H - 2 - gy) : gy);
            gx = (gx < 0) ? -gx : ((gx >= IMG_W) ? (2 * IMG_W - 2 - gx) : gx);
            s_in[idx] = pin[gy * IMG_W + gx];
        }
    }
    __syncthreads();

    // ---- stage 2: horizontal 21-tap, 4 outputs/thread ----
    // output col lx+d (d=0..3) needs s_in cols lx+2+d .. lx+22+d  (skew +2)
    for (int idx = tid; idx < LW * (TILE / 4); idx += NT) {
        int ly = idx >> 4;            // row 0..83
        int lx = (idx & 15) << 2;     // col 0,4,...,60
        const float4* rp = (const float4*)&s_in[ly * LWX + lx];  // 16B aligned
        float v[28];
#pragma unroll
        for (int t = 0; t < 7; ++t) {
            float4 f = rp[t];
            v[4 * t + 0] = f.x; v[4 * t + 1] = f.y;
            v[4 * t + 2] = f.z; v[4 * t + 3] = f.w;
        }
        float a0 = 0.f, a1 = 0.f, a2 = 0.f, a3 = 0.f;
#pragma unroll
        for (int k = 0; k < KS; ++k) {
            float wk = w[k];
            a0 += wk * v[k + 2];
            a1 += wk * v[k + 3];
            a2 += wk * v[k + 4];
            a3 += wk * v[k + 5];
        }
        *(float4*)&s_h[ly * SH + lx] = make_float4(a0, a1, a2, a3);
    }
    __syncthreads();

    // ---- stage 3: vertical 21-tap, 1 col x 16 rows per thread ----
    // Wave lanes cover 64 consecutive columns -> 2-way bank aliasing (free).
    {
        const int c  = tid & 63;              // column 0..63
        const int rb = (tid >> 6) << 4;       // row base 0,16,32,48

        float acc[16];
#pragma unroll
        for (int r = 0; r < 16; ++r) acc[r] = 0.f;

#pragma unroll
        for (int t = 0; t < KS + 15; ++t) {   // 36 s_h rows
            float v = s_h[(rb + t) * SH + c];
#pragma unroll
            for (int r = 0; r < 16; ++r) {
                int k = t - r;
                if (k >= 0 && k < KS) acc[r] += w[k] * v;
            }
        }

        float* __restrict__ pout = out + (size_t)plane * (IMG_H * IMG_W)
                                       + (size_t)(y0 + rb) * IMG_W + (x0 + c);
#pragma unroll
        for (int r = 0; r < 16; ++r) pout[r * IMG_W] = acc[r];  // 256B/wave
    }
}

extern "C" void kernel_launch(void* const* d_in, const int* in_sizes, int n_in,
                              void* d_out, int out_size, void* d_ws, size_t ws_size,
                              hipStream_t stream)
{
    const float* x = (const float*)d_in[0];
    float* out = (float*)d_out;

    dim3 grid(IMG_W / TILE, IMG_H / TILE, 96);   // 8 x 8 x (32*3) planes
    dim3 block(NT);
    gauss_blur_kernel<<<grid, block, 0, stream>>>(x, out);
}

// Round 7
// 201.012 us; speedup vs baseline: 1.5033x; 1.1378x over previous
//
#include <hip/hip_runtime.h>
#include <math.h>

// Gaussian blur 21x21, sigma=5, depthwise [B=32,C=3,H=512,W=512] fp32, reflect pad.
//
// R7 = R6 + sched_barrier(0) race fix.
// R6's in-place stage 2 was correct only if all 10 window ds_reads are EMITTED
// before any ds_write (HW executes a wave's DS ops in order; rows never span
// waves). hipcc broke that: write of output-quad ob depends only on quads
// ob..ob+6, and per-lane the write region is disjoint from quads 7..9, so the
// scheduler hoisted writes above the tail reads -> cross-lane WAR (lane cb
// reads cols cb+32..39 that lanes cb+32 already overwrote). absmax 2.7e-2.
// Fix: __builtin_amdgcn_sched_barrier(0) between load block and compute/write
// (guide rule #18). Zero cost, no extra barrier, no register growth.
//
// Structure (from R6): stage2 sliding window 16 outputs/item, H written
// in-place into s_in cols 0..63; s_h deleted; LDS 30.9 KB -> 5 blocks/CU.

#define KS    21
#define PAD   10
#define TILE  64
#define LW    (TILE + 2 * PAD)   // 84 tile rows (with halo)
#define SKEW  2                  // xbase = x0-12 -> float4-aligned
#define LWX   92                 // s_in row stride (92/4=23 quads)
#define IMG_H 512
#define IMG_W 512
#define NT    256

__global__ __launch_bounds__(NT, 5) void gauss_blur_kernel(
    const float* __restrict__ in, float* __restrict__ out)
{
    __shared__ __align__(16) float s_in[LW * LWX];  // 84*92*4 = 30912 B -> 5 blocks/CU

    // Normalized 1-D Gaussian (outer-product normalization == 1-D norm squared)
    float w[KS];
    {
        float s = 0.f;
#pragma unroll
        for (int k = 0; k < KS; ++k) {
            float d = (float)(k - PAD);
            w[k] = expf(-d * d * (1.0f / 50.0f));  // 2*sigma^2 = 50
            s += w[k];
        }
        float inv = 1.0f / s;
#pragma unroll
        for (int k = 0; k < KS; ++k) w[k] *= inv;
    }

    const int tid   = threadIdx.x;
    const int plane = blockIdx.z;                 // b*C + c, 0..95
    const int x0    = blockIdx.x * TILE;
    const int y0    = blockIdx.y * TILE;
    const int xbase = x0 - PAD - SKEW;            // -12..436, == 0 mod 4

    const float* __restrict__ pin = in + (size_t)plane * (IMG_H * IMG_W);

    // ---- stage 1: global -> LDS ----
    if (xbase >= 0 && xbase + LWX <= IMG_W) {
        // interior in x (bx=1..6): aligned float4 loads, y reflect per row
        for (int idx = tid; idx < LW * (LWX / 4); idx += NT) {
            int ly = idx / (LWX / 4);
            int q  = idx - ly * (LWX / 4);
            int gy = y0 + ly - PAD;
            gy = (gy < 0) ? -gy : ((gy >= IMG_H) ? (2 * IMG_H - 2 - gy) : gy);
            float4 v = *(const float4*)&pin[gy * IMG_W + xbase + 4 * q];
            *(float4*)&s_in[ly * LWX + 4 * q] = v;
        }
    } else {
        // x-edge blocks (bx==0 or 7): scalar reflect path
        for (int idx = tid; idx < LW * LWX; idx += NT) {
            int ly = idx / LWX;
            int j  = idx - ly * LWX;
            int gy = y0 + ly - PAD;
            int gx = xbase + j;
            gy = (gy < 0) ? -gy : ((gy >= IMG_H) ? (2 * IMG_H - 2 - gy) : gy);
            gx = (gx < 0) ? -gx : ((gx >= IMG_W) ? (2 * IMG_W - 2 - gx) : gx);
            s_in[idx] = pin[gy * IMG_W + gx];
        }
    }
    __syncthreads();

    // ---- stage 2: horizontal 21-tap, sliding window, 16 outputs/item ----
    // item = (row y, col-group cb). Output col cb+o (o=0..15) needs s_in cols
    // cb+o+2 .. cb+o+22 (skew +2) -> window cb..cb+39. H written in-place to
    // s_in[y][cb..cb+15]. Row y's 4 items live in ONE wave (tids 4y..4y+3);
    // DS ops execute in emitted order per wave, and sched_barrier(0) pins all
    // 10 reads before the first write -> cross-lane WAR impossible.
#pragma unroll
    for (int it = 0; it < 2; ++it) {
        int idx = tid + it * NT;
        if (idx < LW * 4) {                       // 336 items
            int y  = idx >> 2;                    // row 0..83
            int cb = (idx & 3) << 4;              // 0,16,32,48
            const float4* rp = (const float4*)&s_in[y * LWX + cb];  // aligned
            float v[40];
#pragma unroll
            for (int t = 0; t < 10; ++t) {
                float4 f = rp[t];
                v[4 * t + 0] = f.x; v[4 * t + 1] = f.y;
                v[4 * t + 2] = f.z; v[4 * t + 3] = f.w;
            }
            // Pin: all 10 ds_read_b128 emitted before anything below.
            __builtin_amdgcn_sched_barrier(0);
            float* wp = &s_in[y * LWX + cb];
#pragma unroll
            for (int ob = 0; ob < 4; ++ob) {
                float a0 = 0.f, a1 = 0.f, a2 = 0.f, a3 = 0.f;
#pragma unroll
                for (int k = 0; k < KS; ++k) {
                    float wk = w[k];
                    int b = 4 * ob + 2 + k;
                    a0 += wk * v[b + 0];
                    a1 += wk * v[b + 1];
                    a2 += wk * v[b + 2];
                    a3 += wk * v[b + 3];
                }
                *(float4*)(wp + 4 * ob) = make_float4(a0, a1, a2, a3);
            }
        }
    }
    __syncthreads();

    // ---- stage 3: vertical 21-tap, 1 col x 16 rows per thread ----
    // Reads H from s_in cols 0..63; lanes cover 64 consecutive columns ->
    // conflict-free b32 (stride-agnostic, proven R4). Sliding accumulate.
    {
        const int c  = tid & 63;              // column 0..63
        const int rb = (tid >> 6) << 4;       // row base 0,16,32,48

        float acc[16];
#pragma unroll
        for (int r = 0; r < 16; ++r) acc[r] = 0.f;

#pragma unroll
        for (int t = 0; t < KS + 15; ++t) {   // 36 rows
            float v = s_in[(rb + t) * LWX + c];
#pragma unroll
            for (int r = 0; r < 16; ++r) {
                int k = t - r;
                if (k >= 0 && k < KS) acc[r] += w[k] * v;
            }
        }

        float* __restrict__ pout = out + (size_t)plane * (IMG_H * IMG_W)
                                       + (size_t)(y0 + rb) * IMG_W + (x0 + c);
#pragma unroll
        for (int r = 0; r < 16; ++r) pout[r * IMG_W] = acc[r];  // 256B/wave
    }
}

extern "C" void kernel_launch(void* const* d_in, const int* in_sizes, int n_in,
                              void* d_out, int out_size, void* d_ws, size_t ws_size,
                              hipStream_t stream)
{
    const float* x = (const float*)d_in[0];
    float* out = (float*)d_out;

    dim3 grid(IMG_W / TILE, IMG_H / TILE, 96);   // 8 x 8 x (32*3) planes
    dim3 block(NT);
    gauss_blur_kernel<<<grid, block, 0, stream>>>(x, out);
}